// Round 12
// baseline (162.668 us; speedup 1.0000x reference)
//
#include <hip/hip_runtime.h>
#include <math.h>

#define FMPX 40
#define NPOS 1600          // 40*40
#define NCLS 80
#define NBOX 8000
#define KDIM 512
#define CAP  256           // per-class candidate capacity

// anchor (w,h) pairs
__constant__ float c_aw[5] = {17.f, 55.f, 92.f, 202.f, 289.f};
__constant__ float c_ah[5] = {25.f, 75.f, 206.f, 21.f, 311.f};

__device__ __forceinline__ float sigf(float x) { return 1.0f / (1.0f + expf(-x)); }

// ---------------------------------------------------------------------------
// K1 (R16): P2xR2 pos-blocked GEMM — the clean LDS-instr experiment.
// Evidence: R5 (675blk, R=4) and R15 (1350blk, R=2) both run 42.4 us despite
// 2x occupancy difference; the invariant across them is total wave-level W
// ds_read_b128 count (1.38M) — broadcast granularity is the wave, so only
// covering more POSITIONS per wave cuts it. R12 (P=2,R=4, 351blk) halved LDS
// instrs but collapsed occupancy to 1.4 blk/CU and lost. This round: P=2
// pos x R=2 rows -> per-thread FMA = 2048 (== R5), W-reads/thread = 256 b128
// (half), grid 13x54 = 702 blocks (2.7 blk/CU == R5's proven ratio).
// A-loads are float2 (adjacent positions, 512B/wave coalesced). Tail tile
// (mTile 12) clamps loads to pos 1598, guards stores (R12-verified pattern).
// Per-output FMA chain strictly ascending k, identical operands ->
// bitwise-identical outputs (absmax 2.0 preserved).
// ---------------------------------------------------------------------------
__global__ __launch_bounds__(256) void k_gemm(
    const float* __restrict__ cls_feat, const float* __restrict__ reg_feat,
    const float* __restrict__ w_obj, const float* __restrict__ b_obj,
    const float* __restrict__ w_cls, const float* __restrict__ b_cls,
    const float* __restrict__ w_reg, const float* __restrict__ b_reg,
    float* __restrict__ clsRaw,   // [1600][400]
    float* __restrict__ roRaw)    // [1600][25]: 0..4 obj, 5..24 reg
{
    __shared__ float Ws[8 * KDIM];         // 16 KB
    const int mTile = blockIdx.x;          // 0..12  (128 positions each)
    const int nTile = blockIdx.y;          // 0..53  (8 outs each)
    const int hw0   = mTile * 128;
    const bool isCls = (nTile < 50);
    const float* feat = isCls ? cls_feat : reg_feat;

    const int lane = threadIdx.x & 63;
    const int og   = threadIdx.x >> 6;     // 0..3 (wave-uniform); rows og*2, og*2+1

    // This thread's adjacent position pair.
    const int pA = hw0 + 2 * lane;         // even
    const int pB = pA + 1;                 // odd
    const bool vA = (pA < NPOS);
    const bool vB = (pB < NPOS);
    int pbase = pA;
    if (pbase > NPOS - 2) pbase = NPOS - 2;          // clamp: loads always in-bounds

    // float2 pointer: k stride = NPOS floats = NPOS/2 float2s.
    const float2* ap2 = (const float2*)feat + (pbase >> 1);

    // Initial A prefetch (k=0..15) — independent of W staging, issue early.
    float2 A0[8], A1[8];
#pragma unroll
    for (int t = 0; t < 8; t++) A0[t] = ap2[t * (NPOS / 2)];
#pragma unroll
    for (int t = 0; t < 8; t++) A1[t] = ap2[(8 + t) * (NPOS / 2)];

    // ---- stage W tile [8][512] (coalesced float4; 4 iters/thread) ----
    for (int i = threadIdx.x * 4; i < 8 * KDIM; i += 256 * 4) {
        int r = i >> 9, k = i & 511;
        const float* src;
        bool valid = true;
        if (isCls) {
            src = w_cls + (nTile * 8 + r) * KDIM + k;
        } else {
            int o = (nTile - 50) * 8 + r;    // 0..31
            if (o < 5)       src = w_obj + o * KDIM + k;
            else if (o < 25) src = w_reg + (o - 5) * KDIM + k;
            else           { src = w_obj; valid = false; }
        }
        float4 v = valid ? *(const float4*)src : make_float4(0.f, 0.f, 0.f, 0.f);
        *(float4*)&Ws[i] = v;
    }

    // ---- per-thread output metadata (wave-uniform) ----
    float bias[2];
    bool ok[2];
#pragma unroll
    for (int j = 0; j < 2; j++) {
        int r = og * 2 + j;                // row within the 8-wide tile
        if (isCls) {
            bias[j] = b_cls[nTile * 8 + r]; ok[j] = true;
        } else {
            int o = (nTile - 50) * 8 + r;
            if (o < 5)       { bias[j] = b_obj[o];     ok[j] = true; }
            else if (o < 25) { bias[j] = b_reg[o - 5]; ok[j] = true; }
            else             { bias[j] = 0.0f;         ok[j] = false; }
        }
    }

    __syncthreads();   // Ws ready; only barrier in the kernel

    float accA[2] = {0.f, 0.f};            // pos pA, rows og*2 / og*2+1
    float accB[2] = {0.f, 0.f};            // pos pB
    const float* wsBase = &Ws[(og * 2) * KDIM];

    // Main loop: pairs of 8-k steps; prefetch 16 k ahead. kk = 0..480.
    for (int kk = 0; kk < KDIM - 16; kk += 16) {
        // consume A0 (k = kk..kk+7): each wp[t] feeds BOTH positions
#pragma unroll
        for (int j = 0; j < 2; j++) {
            const float* wp = wsBase + j * KDIM + kk;    // LDS b128 x2, broadcast
            accA[j] += A0[0].x * wp[0]; accA[j] += A0[1].x * wp[1];
            accA[j] += A0[2].x * wp[2]; accA[j] += A0[3].x * wp[3];
            accA[j] += A0[4].x * wp[4]; accA[j] += A0[5].x * wp[5];
            accA[j] += A0[6].x * wp[6]; accA[j] += A0[7].x * wp[7];
            accB[j] += A0[0].y * wp[0]; accB[j] += A0[1].y * wp[1];
            accB[j] += A0[2].y * wp[2]; accB[j] += A0[3].y * wp[3];
            accB[j] += A0[4].y * wp[4]; accB[j] += A0[5].y * wp[5];
            accB[j] += A0[6].y * wp[6]; accB[j] += A0[7].y * wp[7];
        }
#pragma unroll
        for (int t = 0; t < 8; t++) A0[t] = ap2[(kk + 16 + t) * (NPOS / 2)];
        // consume A1 (k = kk+8..kk+15)
#pragma unroll
        for (int j = 0; j < 2; j++) {
            const float* wp = wsBase + j * KDIM + kk + 8;
            accA[j] += A1[0].x * wp[0]; accA[j] += A1[1].x * wp[1];
            accA[j] += A1[2].x * wp[2]; accA[j] += A1[3].x * wp[3];
            accA[j] += A1[4].x * wp[4]; accA[j] += A1[5].x * wp[5];
            accA[j] += A1[6].x * wp[6]; accA[j] += A1[7].x * wp[7];
            accB[j] += A1[0].y * wp[0]; accB[j] += A1[1].y * wp[1];
            accB[j] += A1[2].y * wp[2]; accB[j] += A1[3].y * wp[3];
            accB[j] += A1[4].y * wp[4]; accB[j] += A1[5].y * wp[5];
            accB[j] += A1[6].y * wp[6]; accB[j] += A1[7].y * wp[7];
        }
#pragma unroll
        for (int t = 0; t < 8; t++) A1[t] = ap2[(kk + 24 + t) * (NPOS / 2)];
    }
    // tail: k = 496..511, no prefetch
    {
        const int kk = KDIM - 16;
#pragma unroll
        for (int j = 0; j < 2; j++) {
            const float* wp = wsBase + j * KDIM + kk;
            accA[j] += A0[0].x * wp[0]; accA[j] += A0[1].x * wp[1];
            accA[j] += A0[2].x * wp[2]; accA[j] += A0[3].x * wp[3];
            accA[j] += A0[4].x * wp[4]; accA[j] += A0[5].x * wp[5];
            accA[j] += A0[6].x * wp[6]; accA[j] += A0[7].x * wp[7];
            accB[j] += A0[0].y * wp[0]; accB[j] += A0[1].y * wp[1];
            accB[j] += A0[2].y * wp[2]; accB[j] += A0[3].y * wp[3];
            accB[j] += A0[4].y * wp[4]; accB[j] += A0[5].y * wp[5];
            accB[j] += A0[6].y * wp[6]; accB[j] += A0[7].y * wp[7];
        }
#pragma unroll
        for (int j = 0; j < 2; j++) {
            const float* wp = wsBase + j * KDIM + kk + 8;
            accA[j] += A1[0].x * wp[0]; accA[j] += A1[1].x * wp[1];
            accA[j] += A1[2].x * wp[2]; accA[j] += A1[3].x * wp[3];
            accA[j] += A1[4].x * wp[4]; accA[j] += A1[5].x * wp[5];
            accA[j] += A1[6].x * wp[6]; accA[j] += A1[7].x * wp[7];
            accB[j] += A1[0].y * wp[0]; accB[j] += A1[1].y * wp[1];
            accB[j] += A1[2].y * wp[2]; accB[j] += A1[3].y * wp[3];
            accB[j] += A1[4].y * wp[4]; accB[j] += A1[5].y * wp[5];
            accB[j] += A1[6].y * wp[6]; accB[j] += A1[7].y * wp[7];
        }
    }

    if (isCls) {
        if (vA) {
            float2 rv = make_float2(accA[0] + bias[0], accA[1] + bias[1]);
            *(float2*)&clsRaw[pA * 400 + nTile * 8 + og * 2] = rv;
        }
        if (vB) {
            float2 rv = make_float2(accB[0] + bias[0], accB[1] + bias[1]);
            *(float2*)&clsRaw[pB * 400 + nTile * 8 + og * 2] = rv;
        }
    } else {
#pragma unroll
        for (int j = 0; j < 2; j++) {
            int o = (nTile - 50) * 8 + og * 2 + j;
            if (ok[j]) {
                if (vA) roRaw[pA * 25 + o] = accA[j] + bias[j];
                if (vB) roRaw[pB * 25 + o] = accB[j] + bias[j];
            }
        }
    }
}

// ---------------------------------------------------------------------------
// K2: per-box scores, argmax label, decode, outputs. BYTE-IDENTICAL to the
// R5-verified kernel.
// ---------------------------------------------------------------------------
__global__ __launch_bounds__(256) void k_box(
    const float* __restrict__ clsRaw, const float* __restrict__ roRaw,
    float* __restrict__ out,          // d_out: [32000 bboxes][8000 score][8000 labels][8000 keep]
    float4* __restrict__ nmsBox, float* __restrict__ nmsArea,
    float2* __restrict__ sl)          // packed (score,label) for k_nms scan
{
    const int n = blockIdx.x * 4 + (threadIdx.x >> 6);   // box index 0..7999
    const int lane = threadIdx.x & 63;
    const int hw = n / 5, a = n % 5;

    const float sobj = sigf(roRaw[hw * 25 + a]);
    const float* cbase = clsRaw + hw * 400 + a * 80;

    const int l4 = (lane < 20) ? lane : 19;     // clamp for safe address
    float4 cs = *(const float4*)(cbase + l4 * 4);

    float s0 = sqrtf(sobj * sigf(cs.x));
    float s1 = sqrtf(sobj * sigf(cs.y));
    float s2 = sqrtf(sobj * sigf(cs.z));
    float s3 = sqrtf(sobj * sigf(cs.w));
    float v = s0; int bi = l4 * 4;
    if (s1 > v) { v = s1; bi = l4 * 4 + 1; }
    if (s2 > v) { v = s2; bi = l4 * 4 + 2; }
    if (s3 > v) { v = s3; bi = l4 * 4 + 3; }
    if (lane >= 20) { v = -1.0f; bi = 0x7FFFFFFF; }  // scores are always > 0

#pragma unroll
    for (int off = 32; off >= 1; off >>= 1) {
        float ov = __shfl_xor(v, off);
        int   oi = __shfl_xor(bi, off);
        if (ov > v || (ov == v && oi < bi)) { v = ov; bi = oi; }
    }

    if (lane == 0) {
        const float* rp = roRaw + hw * 25 + 5 + a * 4;
        float r0 = rp[0], r1 = rp[1], r2 = rp[2], r3 = rp[3];
        float gx = (float)(hw % FMPX), gy = (float)(hw / FMPX);
        float cx = (sigf(r0) + gx) * 32.0f;
        float cy = (sigf(r1) + gy) * 32.0f;
        float wv = expf(r2) * c_aw[a];
        float hv = expf(r3) * c_ah[a];
        float x1 = cx - wv * 0.5f, y1 = cy - hv * 0.5f;
        float x2 = cx + wv * 0.5f, y2 = cy + hv * 0.5f;

        out[n * 4 + 0] = x1; out[n * 4 + 1] = y1;
        out[n * 4 + 2] = x2; out[n * 4 + 3] = y2;
        out[32000 + n] = v;
        out[40000 + n] = (float)bi;
        out[48000 + n] = 0.0f;            // keep init (k_nms sets 1s later)
        sl[n] = make_float2(v, (float)bi);

        // b2: reinterpret x1y1x2y2 as cxcywh (faithful to the reference nms())
        float nx1 = x1 - x2 * 0.5f, ny1 = y1 - y2 * 0.5f;
        float nx2 = x1 + x2 * 0.5f, ny2 = y1 + y2 * 0.5f;
        nmsBox[n]  = make_float4(nx1, ny1, nx2, ny2);
        nmsArea[n] = (nx2 - nx1) * (ny2 - ny1);
    }
}

// ---------------------------------------------------------------------------
// K3: VERBATIM the R5-verified k_nms — the fastest measured variant (41.2 us).
// R7-R13 redesigns (wave-argmax, ballot-greedy, edge-matrix, packed keys) all
// lost to it: the 4-wave barrier-interleaved bitonic+greedy hides LDS latency
// via TLP better than any single-wave serial chain. Do not touch.
// ---------------------------------------------------------------------------
__global__ __launch_bounds__(256) void k_nms(
    const float2* __restrict__ sl,
    const float4* __restrict__ nmsBox, const float* __restrict__ nmsArea,
    float* __restrict__ keepOut)
{
    const int c = blockIdx.x;

    __shared__ float ss[CAP];
    __shared__ int   si[CAP];
    __shared__ float bx1[CAP], by1[CAP], bx2[CAP], by2[CAP], bar[CAP];
    __shared__ int   supp[CAP];
    __shared__ int   cnt;

    if (threadIdx.x == 0) cnt = 0;
    __syncthreads();

    for (int i = threadIdx.x; i < NBOX; i += 256) {
        float2 p = sl[i];
        if (p.x >= 0.3f && (int)p.y == c) {
            int q = atomicAdd(&cnt, 1);          // LDS atomic
            if (q < CAP) { ss[q] = p.x; si[q] = i; }
        }
    }
    __syncthreads();

    int m = cnt;
    if (m > CAP) m = CAP;

    // P = next pow2 >= m (min 2); pad with -inf sentinels.
    int P = 2;
    while (P < m) P <<= 1;
    for (int i = threadIdx.x; i < P; i += 256) {
        if (i >= m) { ss[i] = -INFINITY; si[i] = 0x7FFFFFFF; }
    }
    __syncthreads();

    for (int size = 2; size <= P; size <<= 1) {
        for (int stride = size >> 1; stride > 0; stride >>= 1) {
            for (int t = threadIdx.x; t < P / 2; t += 256) {
                int lo = 2 * stride * (t / stride) + (t % stride);
                int hi = lo + stride;
                bool desc = ((lo & size) == 0);
                float slo = ss[lo], shi = ss[hi];
                int   ilo = si[lo], ihi = si[hi];
                bool loBetter = (slo > shi) || (slo == shi && ilo < ihi);
                bool doSwap = desc ? !loBetter : loBetter;
                if (doSwap) { ss[lo] = shi; ss[hi] = slo; si[lo] = ihi; si[hi] = ilo; }
            }
            __syncthreads();
        }
    }

    for (int i = threadIdx.x; i < m; i += 256) {
        int n = si[i];
        float4 b = nmsBox[n];
        bx1[i] = b.x; by1[i] = b.y; bx2[i] = b.z; by2[i] = b.w;
        bar[i] = nmsArea[n];
        supp[i] = 0;
    }
    __syncthreads();

    for (int k = 0; k < m; k++) {
        if (!supp[k]) {
            float kx1 = bx1[k], ky1 = by1[k], kx2 = bx2[k], ky2 = by2[k], ka = bar[k];
            for (int j = k + 1 + threadIdx.x; j < m; j += 256) {
                float xx1 = fmaxf(kx1, bx1[j]);
                float yy1 = fmaxf(ky1, by1[j]);
                float xx2 = fminf(kx2, bx2[j]);
                float yy2 = fminf(ky2, by2[j]);
                float inter = fmaxf(1e-10f, xx2 - xx1) * fmaxf(1e-10f, yy2 - yy1);
                float iou = inter / ((ka + bar[j] - inter) + 1e-14f);
                if (iou > 0.5f) supp[j] = 1;
            }
        }
        __syncthreads();
    }

    for (int j = threadIdx.x; j < m; j += 256) {
        if (!supp[j]) keepOut[si[j]] = 1.0f;
    }
}

// ---------------------------------------------------------------------------
extern "C" void kernel_launch(void* const* d_in, const int* in_sizes, int n_in,
                              void* d_out, int out_size, void* d_ws, size_t ws_size,
                              hipStream_t stream) {
    const float* cls_feat = (const float*)d_in[0];
    const float* reg_feat = (const float*)d_in[1];
    const float* w_obj    = (const float*)d_in[2];
    const float* b_obj    = (const float*)d_in[3];
    const float* w_cls    = (const float*)d_in[4];
    const float* b_cls    = (const float*)d_in[5];
    const float* w_reg    = (const float*)d_in[6];
    const float* b_reg    = (const float*)d_in[7];

    float* out = (float*)d_out;
    float* ws  = (float*)d_ws;

    // workspace layout (floats) — IDENTICAL to the R5-proven layout, 2.944 MB
    float*  clsRaw    = ws;                       // 640000
    float*  roRaw     = ws + 640000;              // 40000
    float4* nmsBox    = (float4*)(ws + 680000);   // 32000 floats (16B-aligned offset)
    float*  nmsArea   = ws + 712000;              // 8000
    float2* sl        = (float2*)(ws + 720000);   // 16000 floats (8B-aligned)
    // total 736000 floats

    k_gemm<<<dim3(13, 54), 256, 0, stream>>>(cls_feat, reg_feat,
                                             w_obj, b_obj, w_cls, b_cls, w_reg, b_reg,
                                             clsRaw, roRaw);
    k_box<<<NBOX / 4, 256, 0, stream>>>(clsRaw, roRaw, out, nmsBox, nmsArea, sl);
    k_nms<<<NCLS, 256, 0, stream>>>(sl, nmsBox, nmsArea, out + 48000);
}